// Round 1
// baseline (19751.418 us; speedup 1.0000x reference)
//
#include <hip/hip_runtime.h>

#define SEQ   1024
#define BATCH 128
#define EMB   512
#define HID   512
#define KDIM  1024   // EMB+HID
#define NZ    2048   // 4*HID

typedef __bf16 bf16;
typedef __attribute__((ext_vector_type(8))) __bf16 bf16x8;
typedef __attribute__((ext_vector_type(4))) __bf16 bf16x4;
typedef __attribute__((ext_vector_type(4))) float f32x4;
typedef __attribute__((ext_vector_type(4))) unsigned int uint4v;

// W [1024][2048] fp32 row-major -> Ws bf16 k-blocked: Ws[(kb*2048 + n)*32 + ko]
__global__ void convert_w(const float* __restrict__ W, bf16* __restrict__ Ws) {
    int idx = blockIdx.x * 256 + threadIdx.x;
    int k = idx >> 11;
    int n = idx & 2047;
    float w = W[idx];
    int kb = k >> 5, ko = k & 31;
    Ws[((kb * NZ + n) << 5) + ko] = (bf16)w;
}

// Persistent LSTM: 256 wgs (1/CU) x 256 thr. wg = (batch-group gb of 32, h-col
// group gc of 8 cols x 4 gates = 32 z-cols). Weights pinned in LDS; c in regs;
// h exchanged through global with per-batch-group 64-wg barriers.
__global__ __launch_bounds__(256) void lstm_persist(
    const float* __restrict__ x,      // [SEQ][BATCH][EMB] fp32
    const bf16*  __restrict__ Ws,     // k-blocked bf16 weights
    const float* __restrict__ bias,   // [2048] fp32
    bf16* h0buf, bf16* h1buf,         // [BATCH][HID] bf16 ping-pong (no restrict!)
    unsigned int* bar,                // 4 counters, 128B apart, zeroed per launch
    float* __restrict__ out)          // [SEQ][BATCH][HID] fp32 (+ hT, cT tail)
{
    // Wlds: frag-lane-linear: [(ch*32+kb)*64 + L] * 8 bf16 -> wave b128 reads
    // are contiguous 1 KiB (conflict-free). 64 KiB.
    __shared__ bf16  Wlds[2 * 32 * 64 * 8];
    __shared__ bf16  Ash[32 * 1032];         // 32 rows x 1024 k, pad->1032. 66 KiB
    __shared__ float zsh[32][33];            // 4.1 KiB    (total 132.6 KiB)

    const int tid  = threadIdx.x;
    const int lane = tid & 63;
    const int ln   = lane & 15;
    const int q    = lane >> 4;
    const int wave = tid >> 6;
    const int mh   = wave & 1;   // M half (16 rows)
    const int chh  = wave >> 1;  // N half (16 z-cols)

    // XCD swizzle: blockIdx%8 = XCD -> batch group gb on XCDs {2gb, 2gb+1}.
    const int xcd = blockIdx.x & 7;
    const int gb  = xcd >> 1;                        // 0..3
    const int gc  = (xcd & 1) * 32 + (blockIdx.x >> 3); // 0..63
    const int m0  = gb * 32;
    const int hc0 = gc * 8;

    // ---- one-time: this wg's 32 z-cols of W (K=1024) into LDS ----
    #pragma unroll
    for (int i = 0; i < 16; ++i) {
        int cI  = tid + i * 256;        // [ch(1) | kb(5) | L(6)]
        int L2  = cI & 63;
        int kb  = (cI >> 6) & 31;
        int ch2 = cI >> 11;
        int cc  = ch2 * 16 + (L2 & 15);                 // local z-col 0..31
        int n   = ((cc >> 3) << 9) + hc0 + (cc & 7);    // gate*512 + hcol
        *(uint4v*)&Wlds[cI * 8] =
            *(const uint4v*)&Ws[((kb * NZ + n) << 5) + ((L2 >> 4) << 3)];
    }

    // elementwise mapping: thread -> (batch-local ml, hcol-local hl)
    const int ml = tid >> 3, hl = tid & 7;
    const float bI = bias[        hc0 + hl];
    const float bF = bias[ 512 + hc0 + hl];
    const float bG = bias[1024 + hc0 + hl];
    const float bO = bias[1536 + hc0 + hl];
    const int gbatch = m0 + ml, ghid = hc0 + hl;
    const size_t hidx = (size_t)gbatch * HID + ghid;
    float c_reg = 0.f;                                  // cell state lives here

    unsigned int* cnt = bar + (gb << 5);                // 128B-spaced counters

    for (int t = 0; t < SEQ; ++t) {
        const bf16* h_in  = (t & 1) ? h1buf : h0buf;
        bf16*       h_out = (t & 1) ? h0buf : h1buf;

        // ---- stage x part of A: k 0..511 (fp32 -> bf16), coalesced ----
        #pragma unroll
        for (int i = 0; i < 16; ++i) {
            int f4  = (tid + i * 256) * 4;   // flat float idx 0..16383
            int row = f4 >> 9;
            int kk  = f4 & 511;
            float4 v = *(const float4*)(x + ((size_t)t * BATCH + m0 + row) * EMB + kk);
            bf16x4 pv = { (bf16)v.x, (bf16)v.y, (bf16)v.z, (bf16)v.w };
            *(bf16x4*)&Ash[row * 1032 + kk] = pv;
        }
        // ---- stage h part of A: k 512..1023 ----
        if (t == 0) {
            #pragma unroll
            for (int i = 0; i < 8; ++i) {
                int e8  = (tid + i * 256) * 8;
                int row = e8 >> 9;
                int kk  = e8 & 511;
                uint4v z = {0u, 0u, 0u, 0u};
                *(uint4v*)&Ash[row * 1032 + 512 + kk] = z;
            }
        } else {
            #pragma unroll
            for (int i = 0; i < 8; ++i) {
                int e8  = (tid + i * 256) * 8;
                int row = e8 >> 9;
                int kk  = e8 & 511;
                *(uint4v*)&Ash[row * 1032 + 512 + kk] =
                    *(const uint4v*)(h_in + (m0 + row) * HID + kk);
            }
        }
        __syncthreads();

        // ---- GEMM: wave computes 16x16 quadrant of the 32x32 z-tile, K=1024 ----
        f32x4 acc = {0.f, 0.f, 0.f, 0.f};
        #pragma unroll 8
        for (int kb = 0; kb < 32; ++kb) {
            bf16x8 a = *(const bf16x8*)&Ash[(mh * 16 + ln) * 1032 + kb * 32 + q * 8];
            bf16x8 b = *(const bf16x8*)&Wlds[(((chh * 32 + kb) << 6) + lane) << 3];
            acc = __builtin_amdgcn_mfma_f32_16x16x32_bf16(a, b, acc, 0, 0, 0);
        }
        // C/D: col=ln, row=q*4+r (m89-verified)
        #pragma unroll
        for (int r = 0; r < 4; ++r)
            zsh[mh * 16 + q * 4 + r][chh * 16 + ln] = acc[r];
        __syncthreads();

        // ---- gates + state ----
        float zi = zsh[ml][     hl] + bI;
        float zf = zsh[ml][ 8 + hl] + bF;
        float zg = zsh[ml][16 + hl] + bG;
        float zo = zsh[ml][24 + hl] + bO;
        float si = 1.f / (1.f + __expf(-zi));
        float sf = 1.f / (1.f + __expf(-zf));
        float so = 1.f / (1.f + __expf(-zo));
        float tg = tanhf(zg);
        c_reg = sf * c_reg + si * tg;
        float hn = so * tanhf(c_reg);

        h_out[hidx] = (bf16)hn;
        out[((size_t)t * BATCH + gbatch) * HID + ghid] = hn;
        if (t == SEQ - 1) {
            out[(size_t)SEQ * BATCH * HID + hidx] = hn;                          // hT
            out[(size_t)SEQ * BATCH * HID + (size_t)BATCH * HID + hidx] = c_reg; // cT
            break;   // uniform; kernel-end flush handles out visibility
        }

        // ---- batch-group barrier (64 wgs): release h_t, acquire others' ----
        __syncthreads();          // drains vmcnt: wg's h stores are at L2
        if (tid == 0) {
            __threadfence();      // agent fence: wb L2 -> h slice at coherence point
            __hip_atomic_fetch_add(cnt, 1u, __ATOMIC_RELEASE, __HIP_MEMORY_SCOPE_AGENT);
            unsigned target = (unsigned)(t + 1) << 6;   // 64 wgs per group
            while (__hip_atomic_load(cnt, __ATOMIC_RELAXED, __HIP_MEMORY_SCOPE_AGENT) < target)
                ;
            __threadfence();      // agent fence: invalidate stale h lines (L1+L2)
        }
        __syncthreads();
    }
}

extern "C" void kernel_launch(void* const* d_in, const int* in_sizes, int n_in,
                              void* d_out, int out_size, void* d_ws, size_t ws_size,
                              hipStream_t stream) {
    const float* x    = (const float*)d_in[0];
    const float* W    = (const float*)d_in[1];
    const float* bias = (const float*)d_in[2];
    float* out = (float*)d_out;

    char* ws = (char*)d_ws;
    bf16* Ws = (bf16*)ws;                                    // 4 MB
    bf16* h0 = (bf16*)(ws + (4 << 20));                      // 128 KB
    bf16* h1 = (bf16*)(ws + (4 << 20) + (128 << 10));        // 128 KB
    unsigned int* cnt = (unsigned int*)(ws + (4 << 20) + (256 << 10)); // 4 x 128B

    hipMemsetAsync(cnt, 0, 4 * 128, stream);   // barrier counters MUST be 0 per replay
    convert_w<<<dim3(8192), dim3(256), 0, stream>>>(W, Ws);

    void* args[] = { (void*)&x, (void*)&Ws, (void*)&bias,
                     (void*)&h0, (void*)&h1, (void*)&cnt, (void*)&out };
    hipLaunchCooperativeKernel((const void*)lstm_persist, dim3(256), dim3(256),
                               args, 0, stream);
}